// Round 5
// baseline (312.574 us; speedup 1.0000x reference)
//
#include <hip/hip_runtime.h>
#include <hip/hip_bf16.h>

// GINConv fused pipeline for MI355X (gfx950), dtype-adaptive.
// out[N,128] = x + relu( Lin2( relu( BN( Lin1( (1+eps)x + scatter_sum(x) ) ) ) ) )
// R10: gather is pinned at the random-line-fetch ceiling (167MB @ ~3.5TB/s,
// ~25G lines/s); can't go faster in isolation. Fuse gather INTO gemm1:
// each block gathers its 64 rows straight into a swizzled LDS A-tile, then
// MFMAs. Removes the h0 25MB store + 25MB load, one launch, and gemm1's
// exposed A-load latency. Reduction LDS unioned onto Wl (dead after MFMA)
// to keep 3 blocks/CU; BN partials relocated to the dead h0 region (bucket
// region is live during the fused kernel).

typedef __attribute__((ext_vector_type(8))) short short8;
typedef __attribute__((ext_vector_type(4))) float f32x4;

static __device__ __forceinline__ float bf2f(unsigned short u) {
    union { unsigned int i; float f; } z; z.i = ((unsigned int)u) << 16; return z.f;
}
static __device__ __forceinline__ unsigned short f2bf(float f) {
    unsigned int u = __float_as_uint(f);
    unsigned int lsb = (u >> 16) & 1u;
    u += 0x7fffu + lsb;            // round-to-nearest-even
    return (unsigned short)(u >> 16);
}
static __device__ __forceinline__ void atomAdd(float* p, float v) {
    __hip_atomic_fetch_add(p, v, __ATOMIC_RELAXED, __HIP_MEMORY_SCOPE_AGENT);
}
static __device__ __forceinline__ float lo16(unsigned int u) { return bf2f((unsigned short)(u & 0xffffu)); }
static __device__ __forceinline__ float hi16(unsigned int u) { return bf2f((unsigned short)(u >> 16)); }

// flags[0]: 0 = float tensors bf16, 1 = fp32.  flags[1]: 1 = edge_index int64.
// Also zeros counts[N] and stats[256].
__global__ __launch_bounds__(256) void k_detect(const unsigned short* __restrict__ gamma,
                                                const int* __restrict__ ei,
                                                int* __restrict__ flags,
                                                float* __restrict__ stats,
                                                int* __restrict__ counts, int N) {
    int idx = blockIdx.x * 256 + threadIdx.x;
    if (idx < N) counts[idx] = 0;
    if (blockIdx.x == 0) {
        int t = threadIdx.x;
        if (t < 256) stats[t] = 0.0f;
        if (t == 0) {
            flags[0] = (gamma[0] == 0x3F80u) ? 0 : 1;
            int odd = ei[1] | ei[3] | ei[5] | ei[7] | ei[9] | ei[11] | ei[13] | ei[15];
            flags[1] = (odd == 0) ? 1 : 0;
        }
    }
}

// ---------------- degree histogram over dst ----------------
__global__ __launch_bounds__(256) void k_hist(const int* __restrict__ ei, int* __restrict__ counts,
                                              int E, const int* __restrict__ flags) {
    int e = blockIdx.x * 256 + threadIdx.x;
    if (e >= E) return;
    int dst = flags[1] ? ei[2 * E + 2 * e] : ei[E + e];
    atomicAdd(&counts[dst], 1);
}

// ---------------- two-level exclusive scan of counts[N] -> rowptr[N+1] ----------------
__global__ __launch_bounds__(256) void k_scan1(const int* __restrict__ counts, int* __restrict__ partA,
                                               int N) {
    __shared__ int sd[256];
    int t = threadIdx.x, idx = blockIdx.x * 256 + t;
    sd[t] = (idx < N) ? counts[idx] : 0;
    __syncthreads();
    for (int off = 128; off > 0; off >>= 1) {
        if (t < off) sd[t] += sd[t + off];
        __syncthreads();
    }
    if (t == 0) partA[blockIdx.x] = sd[0];
}

__global__ __launch_bounds__(512) void k_scan2(const int* __restrict__ partA, int* __restrict__ partB,
                                               int NB) {
    __shared__ int sd[512];
    int t = threadIdx.x;
    sd[t] = (t < NB) ? partA[t] : 0;
    __syncthreads();
    for (int off = 1; off < 512; off <<= 1) {
        int v = (t >= off) ? sd[t - off] : 0;
        __syncthreads();
        sd[t] += v;
        __syncthreads();
    }
    if (t < NB) partB[t] = sd[t] - partA[t];   // exclusive prefix
}

// writes rowptr[idx] (exclusive), rowptr[N]=E, and rewrites counts[idx] as cursor
__global__ __launch_bounds__(256) void k_scan3(int* __restrict__ counts, int* __restrict__ rowptr,
                                               const int* __restrict__ partB, int N) {
    __shared__ int sd[256];
    int t = threadIdx.x, idx = blockIdx.x * 256 + t;
    int c = (idx < N) ? counts[idx] : 0;
    sd[t] = c;
    __syncthreads();
    for (int off = 1; off < 256; off <<= 1) {
        int v = (t >= off) ? sd[t - off] : 0;
        __syncthreads();
        sd[t] += v;
        __syncthreads();
    }
    int offB = partB[blockIdx.x];
    int excl = offB + sd[t] - c;
    if (idx < N) {
        rowptr[idx] = excl;
        counts[idx] = excl;                    // becomes fill cursor
        if (idx == N - 1) rowptr[N] = excl + c;
    }
}

// ---------------- bucket fill: bucket[cursor[dst]++] = src ----------------
__global__ __launch_bounds__(256) void k_fill(const int* __restrict__ ei, int* __restrict__ cursor,
                                              int* __restrict__ bucket, int E,
                                              const int* __restrict__ flags) {
    int e = blockIdx.x * 256 + threadIdx.x;
    if (e >= E) return;
    int src, dst;
    if (flags[1]) { src = ei[2 * e]; dst = ei[2 * E + 2 * e]; }
    else          { src = ei[e];     dst = ei[E + e]; }
    int pos = atomicAdd(&cursor[dst], 1);
    bucket[pos] = src;
}

// Stage 128x128 weights into LDS in MFMA-fragment order:
// chunk c (0..2047): li=c&15, kg=(c>>4)&15, t=c>>8 ; n=t*16+li, k0=kg*8.
static __device__ __forceinline__ void stageW(const void* W, unsigned short* Wl,
                                              int tid, int mode) {
    for (int c = tid; c < 2048; c += 256) {
        int li = c & 15, kg = (c >> 4) & 15, t = c >> 8;
        int srcOff = (t * 16 + li) * 128 + kg * 8;
        if (mode == 0) {
            *(short8*)&Wl[c * 8] = *(const short8*)((const unsigned short*)W + srcOff);
        } else {
            const float4* wf = (const float4*)((const float*)W + srcOff);
            float4 f0 = wf[0], f1 = wf[1];
            union { short8 v; unsigned short s[8]; } u;
            u.s[0] = f2bf(f0.x); u.s[1] = f2bf(f0.y); u.s[2] = f2bf(f0.z); u.s[3] = f2bf(f0.w);
            u.s[4] = f2bf(f1.x); u.s[5] = f2bf(f1.y); u.s[6] = f2bf(f1.z); u.s[7] = f2bf(f1.w);
            *(short8*)&Wl[c * 8] = u.v;
        }
    }
}

// ---------------- FUSED gather + h1 = bf16( h0 @ W1^T + b1 ) + BN partials ------
// 64 rows/block, 4 waves; wave gathers its 16 rows into swizzled LDS A-tile:
//   At[lr*64 + ((f>>2)^(lr&15))*4 + (f&3)]  (uint granularity; 2-way banks)
// then MFMAs from LDS. rowptr fetched once per wave (vector load + shfl);
// next node's bucket window prefetched one node ahead.
__global__ __launch_bounds__(256, 3) void k_gemm1(const void* __restrict__ x,
                                                  const void* __restrict__ eps,
                                                  const int* __restrict__ rowptr,
                                                  const int* __restrict__ bucket,
                                                  const void* __restrict__ W1,
                                                  const void* __restrict__ b1,
                                                  unsigned short* __restrict__ h1,
                                                  float* __restrict__ partials,
                                                  int N, const int* __restrict__ flags) {
    __shared__ unsigned short Wl[16384];     // 32KB
    __shared__ unsigned int At[4096];        // 16KB swizzled A tile (64 rows x 64 uints)
    __shared__ float bl[128];
    int tid = threadIdx.x;
    int mode = flags[0];
    int lane = tid & 63, wave = tid >> 6;
    int li = lane & 15, q = lane >> 4;
    int r0 = blockIdx.x * 64 + wave * 16;

    // per-wave rowptr window [r0, r0+16]
    int rl = lane < 16 ? lane : 16;
    int rq = r0 + rl; if (rq > N) rq = N;
    int rpv = rowptr[rq];

    stageW(W1, Wl, tid, mode);
    if (tid < 128)
        bl[tid] = mode ? ((const float*)b1)[tid] : bf2f(((const unsigned short*)b1)[tid]);

    // ---------- gather 16 rows into At ----------
    if (mode == 0) {
        const unsigned int* xr = (const unsigned int*)x;
        float s = 1.0f + bf2f(((const unsigned short*)eps)[0]);
        int begN = __shfl(rpv, 0), endN = __shfl(rpv, 1);
        int idxN = 0;
        { int l0 = endN - begN; if (l0 > 64) l0 = 64;
          if (lane < l0) idxN = bucket[begN + lane]; }
        for (int node = 0; node < 16; ++node) {
            int row = r0 + node;
            int rowc = row < N ? row : N - 1;
            int beg = begN, end = endN, idx = idxN;
            if (node < 15) {
                begN = __shfl(rpv, node + 1); endN = __shfl(rpv, node + 2);
                int ln = endN - begN; if (ln > 64) ln = 64;
                idxN = (lane < ln) ? bucket[begN + lane] : 0;
            }
            unsigned int su = xr[(size_t)rowc * 64 + lane];
            int len = end - beg;
            float ax = 0.f, ay = 0.f;
            for (int base = 0; base < len; base += 64) {
                int rem = len - base; if (rem > 64) rem = 64;
                int idw = (base == 0) ? idx
                        : ((lane < rem) ? bucket[beg + base + lane] : 0);
                int j = 0;
                for (; j + 8 <= rem; j += 8) {
                    int s0 = __shfl(idw, j),     s1 = __shfl(idw, j + 1);
                    int s2 = __shfl(idw, j + 2), s3 = __shfl(idw, j + 3);
                    int s4 = __shfl(idw, j + 4), s5 = __shfl(idw, j + 5);
                    int s6 = __shfl(idw, j + 6), s7 = __shfl(idw, j + 7);
                    unsigned int u0 = xr[(size_t)s0 * 64 + lane];
                    unsigned int u1 = xr[(size_t)s1 * 64 + lane];
                    unsigned int u2 = xr[(size_t)s2 * 64 + lane];
                    unsigned int u3 = xr[(size_t)s3 * 64 + lane];
                    unsigned int u4 = xr[(size_t)s4 * 64 + lane];
                    unsigned int u5 = xr[(size_t)s5 * 64 + lane];
                    unsigned int u6 = xr[(size_t)s6 * 64 + lane];
                    unsigned int u7 = xr[(size_t)s7 * 64 + lane];
                    ax += ((lo16(u0) + lo16(u1)) + (lo16(u2) + lo16(u3)))
                        + ((lo16(u4) + lo16(u5)) + (lo16(u6) + lo16(u7)));
                    ay += ((hi16(u0) + hi16(u1)) + (hi16(u2) + hi16(u3)))
                        + ((hi16(u4) + hi16(u5)) + (hi16(u6) + hi16(u7)));
                }
                if (j + 4 <= rem) {
                    int s0 = __shfl(idw, j),     s1 = __shfl(idw, j + 1);
                    int s2 = __shfl(idw, j + 2), s3 = __shfl(idw, j + 3);
                    unsigned int u0 = xr[(size_t)s0 * 64 + lane];
                    unsigned int u1 = xr[(size_t)s1 * 64 + lane];
                    unsigned int u2 = xr[(size_t)s2 * 64 + lane];
                    unsigned int u3 = xr[(size_t)s3 * 64 + lane];
                    ax += (lo16(u0) + lo16(u1)) + (lo16(u2) + lo16(u3));
                    ay += (hi16(u0) + hi16(u1)) + (hi16(u2) + hi16(u3));
                    j += 4;
                }
                if (j + 2 <= rem) {
                    int s0 = __shfl(idw, j), s1 = __shfl(idw, j + 1);
                    unsigned int u0 = xr[(size_t)s0 * 64 + lane];
                    unsigned int u1 = xr[(size_t)s1 * 64 + lane];
                    ax += lo16(u0) + lo16(u1);
                    ay += hi16(u0) + hi16(u1);
                    j += 2;
                }
                if (j < rem) {
                    unsigned int u = xr[(size_t)__shfl(idw, j) * 64 + lane];
                    ax += lo16(u); ay += hi16(u);
                }
            }
            ax = fmaf(s, lo16(su), ax);
            ay = fmaf(s, hi16(su), ay);
            int lr = wave * 16 + node;
            At[lr * 64 + (((lane >> 2) ^ (lr & 15)) << 2) + (lane & 3)] =
                (unsigned int)f2bf(ax) | ((unsigned int)f2bf(ay) << 16);
        }
    } else {
        const float2* xr = (const float2*)x;
        float s = 1.0f + ((const float*)eps)[0];
        int begN = __shfl(rpv, 0), endN = __shfl(rpv, 1);
        int idxN = 0;
        { int l0 = endN - begN; if (l0 > 64) l0 = 64;
          if (lane < l0) idxN = bucket[begN + lane]; }
        for (int node = 0; node < 16; ++node) {
            int row = r0 + node;
            int rowc = row < N ? row : N - 1;
            int beg = begN, end = endN, idx = idxN;
            if (node < 15) {
                begN = __shfl(rpv, node + 1); endN = __shfl(rpv, node + 2);
                int ln = endN - begN; if (ln > 64) ln = 64;
                idxN = (lane < ln) ? bucket[begN + lane] : 0;
            }
            float2 sv = xr[(size_t)rowc * 64 + lane];
            int len = end - beg;
            float ax = 0.f, ay = 0.f;
            for (int base = 0; base < len; base += 64) {
                int rem = len - base; if (rem > 64) rem = 64;
                int idw = (base == 0) ? idx
                        : ((lane < rem) ? bucket[beg + base + lane] : 0);
                int j = 0;
                for (; j + 8 <= rem; j += 8) {
                    int s0 = __shfl(idw, j),     s1 = __shfl(idw, j + 1);
                    int s2 = __shfl(idw, j + 2), s3 = __shfl(idw, j + 3);
                    int s4 = __shfl(idw, j + 4), s5 = __shfl(idw, j + 5);
                    int s6 = __shfl(idw, j + 6), s7 = __shfl(idw, j + 7);
                    float2 v0 = xr[(size_t)s0 * 64 + lane];
                    float2 v1 = xr[(size_t)s1 * 64 + lane];
                    float2 v2 = xr[(size_t)s2 * 64 + lane];
                    float2 v3 = xr[(size_t)s3 * 64 + lane];
                    float2 v4 = xr[(size_t)s4 * 64 + lane];
                    float2 v5 = xr[(size_t)s5 * 64 + lane];
                    float2 v6 = xr[(size_t)s6 * 64 + lane];
                    float2 v7 = xr[(size_t)s7 * 64 + lane];
                    ax += ((v0.x + v1.x) + (v2.x + v3.x)) + ((v4.x + v5.x) + (v6.x + v7.x));
                    ay += ((v0.y + v1.y) + (v2.y + v3.y)) + ((v4.y + v5.y) + (v6.y + v7.y));
                }
                if (j + 4 <= rem) {
                    int s0 = __shfl(idw, j),     s1 = __shfl(idw, j + 1);
                    int s2 = __shfl(idw, j + 2), s3 = __shfl(idw, j + 3);
                    float2 v0 = xr[(size_t)s0 * 64 + lane];
                    float2 v1 = xr[(size_t)s1 * 64 + lane];
                    float2 v2 = xr[(size_t)s2 * 64 + lane];
                    float2 v3 = xr[(size_t)s3 * 64 + lane];
                    ax += (v0.x + v1.x) + (v2.x + v3.x);
                    ay += (v0.y + v1.y) + (v2.y + v3.y);
                    j += 4;
                }
                for (; j < rem; ++j) {
                    float2 v = xr[(size_t)__shfl(idw, j) * 64 + lane];
                    ax += v.x; ay += v.y;
                }
            }
            ax = fmaf(s, sv.x, ax);
            ay = fmaf(s, sv.y, ay);
            int lr = wave * 16 + node;
            At[lr * 64 + (((lane >> 2) ^ (lr & 15)) << 2) + (lane & 3)] =
                (unsigned int)f2bf(ax) | ((unsigned int)f2bf(ay) << 16);
        }
    }
    __syncthreads();

    // ---------- MFMA from LDS ----------
    int lrb = wave * 16 + li;                 // this lane's A row in the tile
    f32x4 acc[8] = {};
#pragma unroll
    for (int c4 = 0; c4 < 4; ++c4) {
        int k = c4 * 4 + q;
        short8 av = *(const short8*)&At[lrb * 64 + ((k ^ li) << 2)];
#pragma unroll
        for (int t = 0; t < 8; ++t) {
            short8 bfrag = *(const short8*)&Wl[(t * 256 + k * 16 + li) * 8];
            acc[t] = __builtin_amdgcn_mfma_f32_16x16x32_bf16(av, bfrag, acc[t], 0, 0, 0);
        }
    }

    // ---------- epilogue: h1 store + BN partial accumulation ----------
    int m0 = r0;
    float s_acc[8] = {0.f, 0.f, 0.f, 0.f, 0.f, 0.f, 0.f, 0.f};
    float s2_acc[8] = {0.f, 0.f, 0.f, 0.f, 0.f, 0.f, 0.f, 0.f};
    bool full = (m0 + 16 <= N);
    if (full) {
        unsigned short* hp = h1 + (size_t)(m0 + q * 4) * 128 + li;
#pragma unroll
        for (int t = 0; t < 8; ++t) {
            float bb = bl[t * 16 + li];
#pragma unroll
            for (int r = 0; r < 4; ++r) {
                float v = acc[t][r] + bb;
                hp[(size_t)r * 128 + t * 16] = f2bf(v);
                s_acc[t] += v; s2_acc[t] += v * v;
            }
        }
    } else if (m0 < N) {
#pragma unroll
        for (int t = 0; t < 8; ++t) {
            int col = t * 16 + li;
            float bb = bl[col];
#pragma unroll
            for (int r = 0; r < 4; ++r) {
                int row = m0 + q * 4 + r;
                if (row < N) {
                    float v = acc[t][r] + bb;
                    h1[(size_t)row * 128 + col] = f2bf(v);
                    s_acc[t] += v; s2_acc[t] += v * v;
                }
            }
        }
    }
    __syncthreads();                           // Wl/At now dead everywhere
    float* redu = (float*)Wl;                  // [4][128] sums, [4][128] ssq
#pragma unroll
    for (int t = 0; t < 8; ++t) {
        float s = s_acc[t], s2 = s2_acc[t];
        s  += __shfl_xor(s, 16);  s  += __shfl_xor(s, 32);
        s2 += __shfl_xor(s2, 16); s2 += __shfl_xor(s2, 32);
        if (lane < 16) {
            redu[wave * 128 + t * 16 + li] = s;
            redu[512 + wave * 128 + t * 16 + li] = s2;
        }
    }
    __syncthreads();
    float pv;
    if (tid < 128) {
        pv = redu[tid] + redu[128 + tid] + redu[256 + tid] + redu[384 + tid];
    } else {
        int c = tid - 128 + 512;
        pv = redu[c] + redu[128 + c] + redu[256 + c] + redu[384 + c];
    }
    partials[(size_t)blockIdx.x * 256 + tid] = pv;
}

// ---------------- reduce per-block partials -> stats[256] ----------------
__global__ __launch_bounds__(256) void k_reduce(const float* __restrict__ partials,
                                                float* __restrict__ stats, int nb) {
    int t = threadIdx.x;
    float acc = 0.f;
    for (int b = blockIdx.x; b < nb; b += 64)
        acc += partials[(size_t)b * 256 + t];
    atomAdd(&stats[t], acc);
}

// ---------------- out = x + relu( relu(h1*a+c) @ W2^T + b2 ) ----------------
// BN fold (a,c from stats) in prologue; 64 rows/block, 1 tile/wave.
__global__ __launch_bounds__(256, 4) void k_gemm2(const unsigned short* __restrict__ h1,
                                                  const void* __restrict__ W2,
                                                  const void* __restrict__ b2,
                                                  const float* __restrict__ stats,
                                                  const void* __restrict__ gamma,
                                                  const void* __restrict__ beta,
                                                  const void* __restrict__ x,
                                                  void* __restrict__ out, int N, float invN,
                                                  const int* __restrict__ flags) {
    __shared__ unsigned short Wl[16384];
    __shared__ float bl[128], al[128], cl[128];
    int tid = threadIdx.x;
    int mode = flags[0];
    int lane = tid & 63, wave = tid >> 6;
    int li = lane & 15, q = lane >> 4;

    int m0 = blockIdx.x * 64 + wave * 16;
    int rowA = m0 + li; if (rowA >= N) rowA = N - 1;
    const unsigned short* ap = h1 + (size_t)rowA * 128 + q * 8;
    short8 hv[4];
    hv[0] = *(const short8*)(ap);
    hv[1] = *(const short8*)(ap + 32);
    hv[2] = *(const short8*)(ap + 64);
    hv[3] = *(const short8*)(ap + 96);

    stageW(W2, Wl, tid, mode);
    if (tid < 128) {
        bl[tid] = mode ? ((const float*)b2)[tid] : bf2f(((const unsigned short*)b2)[tid]);
        float mean = stats[tid] * invN;
        float var = stats[128 + tid] * invN - mean * mean;
        float g  = mode ? ((const float*)gamma)[tid] : bf2f(((const unsigned short*)gamma)[tid]);
        float bt = mode ? ((const float*)beta)[tid]  : bf2f(((const unsigned short*)beta)[tid]);
        float a = g * rsqrtf(var + 1e-5f);
        al[tid] = a;
        cl[tid] = bt - mean * a;
    }
    __syncthreads();

    // BN + ReLU transform of the A fragments (in registers)
    short8 au[4];
#pragma unroll
    for (int c4 = 0; c4 < 4; ++c4) {
        int k0 = c4 * 32 + q * 8;
        union { short8 v; unsigned short s[8]; } hu; hu.v = hv[c4];
        float4 sa = *(const float4*)&al[k0];
        float4 sb = *(const float4*)&al[k0 + 4];
        float4 ca = *(const float4*)&cl[k0];
        float4 cb = *(const float4*)&cl[k0 + 4];
        union { short8 v; unsigned short s[8]; } uu;
        uu.s[0] = f2bf(fmaxf(fmaf(bf2f(hu.s[0]), sa.x, ca.x), 0.f));
        uu.s[1] = f2bf(fmaxf(fmaf(bf2f(hu.s[1]), sa.y, ca.y), 0.f));
        uu.s[2] = f2bf(fmaxf(fmaf(bf2f(hu.s[2]), sa.z, ca.z), 0.f));
        uu.s[3] = f2bf(fmaxf(fmaf(bf2f(hu.s[3]), sa.w, ca.w), 0.f));
        uu.s[4] = f2bf(fmaxf(fmaf(bf2f(hu.s[4]), sb.x, cb.x), 0.f));
        uu.s[5] = f2bf(fmaxf(fmaf(bf2f(hu.s[5]), sb.y, cb.y), 0.f));
        uu.s[6] = f2bf(fmaxf(fmaf(bf2f(hu.s[6]), sb.z, cb.z), 0.f));
        uu.s[7] = f2bf(fmaxf(fmaf(bf2f(hu.s[7]), sb.w, cb.w), 0.f));
        au[c4] = uu.v;
    }

    bool full = (m0 + 16 <= N);
    float xv[32];
    if (full) {
        if (mode == 0) {
            const unsigned short* xp = (const unsigned short*)x + (size_t)(m0 + q * 4) * 128 + li;
#pragma unroll
            for (int t = 0; t < 8; ++t)
#pragma unroll
                for (int r = 0; r < 4; ++r)
                    xv[t * 4 + r] = bf2f(xp[(size_t)r * 128 + t * 16]);
        } else {
            const float* xp = (const float*)x + (size_t)(m0 + q * 4) * 128 + li;
#pragma unroll
            for (int t = 0; t < 8; ++t)
#pragma unroll
                for (int r = 0; r < 4; ++r)
                    xv[t * 4 + r] = xp[(size_t)r * 128 + t * 16];
        }
    }

    f32x4 acc[8] = {};
#pragma unroll
    for (int c4 = 0; c4 < 4; ++c4) {
#pragma unroll
        for (int t = 0; t < 8; ++t) {
            short8 bfrag = *(const short8*)&Wl[(t * 256 + (c4 * 4 + q) * 16 + li) * 8];
            acc[t] = __builtin_amdgcn_mfma_f32_16x16x32_bf16(au[c4], bfrag, acc[t], 0, 0, 0);
        }
    }

    if (full) {
        if (mode == 0) {
            unsigned short* op = (unsigned short*)out + (size_t)(m0 + q * 4) * 128 + li;
#pragma unroll
            for (int t = 0; t < 8; ++t) {
                float bb = bl[t * 16 + li];
#pragma unroll
                for (int r = 0; r < 4; ++r)
                    op[(size_t)r * 128 + t * 16] =
                        f2bf(xv[t * 4 + r] + fmaxf(acc[t][r] + bb, 0.f));
            }
        } else {
            float* op = (float*)out + (size_t)(m0 + q * 4) * 128 + li;
#pragma unroll
            for (int t = 0; t < 8; ++t) {
                float bb = bl[t * 16 + li];
#pragma unroll
                for (int r = 0; r < 4; ++r)
                    op[(size_t)r * 128 + t * 16] =
                        xv[t * 4 + r] + fmaxf(acc[t][r] + bb, 0.f);
            }
        }
    } else if (m0 < N) {
#pragma unroll
        for (int t = 0; t < 8; ++t) {
            int col = t * 16 + li;
            float bb = bl[col];
#pragma unroll
            for (int r = 0; r < 4; ++r) {
                int row = m0 + q * 4 + r;
                if (row < N) {
                    size_t idx = (size_t)row * 128 + col;
                    float v = fmaxf(acc[t][r] + bb, 0.f);
                    if (mode == 0) {
                        float xvs = bf2f(((const unsigned short*)x)[idx]);
                        ((unsigned short*)out)[idx] = f2bf(xvs + v);
                    } else {
                        float xvs = ((const float*)x)[idx];
                        ((float*)out)[idx] = xvs + v;
                    }
                }
            }
        }
    }
}

extern "C" void kernel_launch(void* const* d_in, const int* in_sizes, int n_in,
                              void* d_out, int out_size, void* d_ws, size_t ws_size,
                              hipStream_t stream) {
    const void* x     = d_in[0];
    const int*  ei    = (const int*)d_in[1];
    const void* eps   = d_in[2];
    const void* W1    = d_in[3];
    const void* b1    = d_in[4];
    const void* gamma = d_in[5];
    const void* beta  = d_in[6];
    const void* W2    = d_in[7];
    const void* b2    = d_in[8];

    int N = in_sizes[0] / 128;
    int E = in_sizes[1] / 2;

    unsigned short* h0 = (unsigned short*)d_ws;      // DEAD data region (reused for partials)
    unsigned short* h1 = h0 + (size_t)N * 128;       // [N,128] bf16 Lin1 out
    int* counts = (int*)(h1 + (size_t)N * 128);      // [N]  (becomes fill cursor)
    int* rowptr = counts + N;                        // [N+1]
    int* bucket = rowptr + N + 1;                    // [E]
    int* partA  = bucket + E;                        // [512]
    int* partB  = partA + 512;                       // [512]
    float* stats = (float*)(partB + 512);            // sum[128] ssq[128]
    int*   flags = (int*)(stats + 256);              // dtype flags

    int NB = (N + 255) / 256;                        // scan blocks (<=512)
    int EB = (E + 255) / 256;
    int mb = (N + 63) / 64;                          // gemm blocks

    // BN partials [mb][256] live in the h0 region (no longer used for data;
    // bucket/rowptr stay live inside the fused gemm1, so they can't be reused).
    float* partials = (float*)h0;

    k_detect<<<NB, 256, 0, stream>>>((const unsigned short*)gamma, ei, flags, stats, counts, N);
    k_hist<<<EB, 256, 0, stream>>>(ei, counts, E, flags);
    k_scan1<<<NB, 256, 0, stream>>>(counts, partA, N);
    k_scan2<<<1, 512, 0, stream>>>(partA, partB, NB);
    k_scan3<<<NB, 256, 0, stream>>>(counts, rowptr, partB, N);
    k_fill<<<EB, 256, 0, stream>>>(ei, counts, bucket, E, flags);

    k_gemm1<<<mb, 256, 0, stream>>>(x, eps, rowptr, bucket, W1, b1, h1,
                                    partials, N, flags);
    k_reduce<<<64, 256, 0, stream>>>(partials, stats, mb);
    k_gemm2<<<mb, 256, 0, stream>>>(h1, W2, b2, stats, gamma, beta, x, d_out, N,
                                    1.0f / (float)N, flags);
}